// Round 6
// baseline (449.685 us; speedup 1.0000x reference)
//
#include <hip/hip_runtime.h>

// out[b,s,j] = sum_k x[b,s,k] * w_concat[inv_perm[j], k] + bias[j]
// INT8 path: weights exact in i8; x per-token quantized (sx = absmax/127).
// Round 5: LDS-FREE GEMM. A and B are pre-packed into MFMA fragment-tiled
// layouts (16KB per 256x64 K-tile, fragment-linear), so every operand load is
// a fully coalesced 1KB wave global_load_dwordx4 straight into VGPRs.
// No barriers, no ds_read, uniform counted vmcnt(10), 4 MFMA clusters/K-tile.

#define M_TOK 16384
#define N_O   4096
#define K_IN  4096
#define N8F   2048
#define NT    64          // K-tiles of 64 bytes (k-elems)

typedef __attribute__((ext_vector_type(4))) int i32x4;

__device__ __forceinline__ int clampq(float f) {
  int q = (int)rintf(f);
  return q > 127 ? 127 : (q < -127 ? -127 : q);
}

// ---------------- pass 1: per-token absmax + quantize (token-major) ----------------
__global__ void prep1_kernel(const float* __restrict__ x,
                             float* __restrict__ sx, char* __restrict__ xq_tok) {
  __shared__ float red[4];
  const int t = threadIdx.x;
  const int T = blockIdx.x;
  const float4* xr = (const float4*)(x + (size_t)T * K_IN);
  float4 v[4];
  float m = 0.f;
#pragma unroll
  for (int i = 0; i < 4; ++i) {
    v[i] = xr[t * 4 + i];
    m = fmaxf(m, fmaxf(fmaxf(fabsf(v[i].x), fabsf(v[i].y)),
                       fmaxf(fabsf(v[i].z), fabsf(v[i].w))));
  }
#pragma unroll
  for (int o = 32; o; o >>= 1) m = fmaxf(m, __shfl_xor(m, o));
  if ((t & 63) == 0) red[t >> 6] = m;
  __syncthreads();
  m = fmaxf(fmaxf(red[0], red[1]), fmaxf(red[2], red[3]));
  const float rq = m > 0.f ? 127.f / m : 0.f;
  if (t == 0) sx[T] = m * (1.f / 127.f);
  unsigned dw[4];
#pragma unroll
  for (int i = 0; i < 4; ++i) {
    int a0 = clampq(v[i].x * rq), a1 = clampq(v[i].y * rq);
    int a2 = clampq(v[i].z * rq), a3 = clampq(v[i].w * rq);
    dw[i] = (a0 & 255) | ((a1 & 255) << 8) | ((a2 & 255) << 16)
          | ((unsigned)(a3 & 255) << 24);
  }
  *(uint4*)(xq_tok + (size_t)T * K_IN + t * 16) = make_uint4(dw[0], dw[1], dw[2], dw[3]);
}

// Fragment-tiled layout (per 256-row-block rb, per K-tile kt): 16KB tile at
// (rb*64+kt)*16384, byte idx16*16 where idx16 = wr*512 + fm*64 + l,
// content = row (wr*128+fm*16+(l&15)), k-bytes [kt*64+(l>>4)*16, +16).

// ---------------- pack W -> fragment-tiled i8 (with inv_perm + scale) ----------------
__global__ void packw_kernel(const int* __restrict__ q8, const float* __restrict__ s8,
                             const int* __restrict__ q4, const float* __restrict__ s4,
                             const int* __restrict__ inv,
                             char* __restrict__ Wq_t, float* __restrict__ scale) {
  __shared__ __align__(16) char lds[256 * 80];   // 80B rows: 16B-aligned, 2-way banks
  const int bn = blockIdx.x >> 6, kt = blockIdx.x & 63;
  const int t = threadIdx.x;
  const int j = bn * 256 + t;
  const int c = inv[j];
  const int* src; float s;
  if (c < N8F) { src = q8 + (size_t)c * K_IN;         s = s8[c]; }
  else         { src = q4 + (size_t)(c - N8F) * K_IN; s = s4[c - N8F]; }
  if (kt == 0) scale[j] = s;
  unsigned dw[16];
#pragma unroll
  for (int i = 0; i < 16; ++i) {
    int4 v = *(const int4*)(src + kt * 64 + i * 4);
    dw[i] = (v.x & 255) | ((v.y & 255) << 8) | ((v.z & 255) << 16)
          | ((unsigned)(v.w & 255) << 24);
  }
#pragma unroll
  for (int i = 0; i < 4; ++i)
    *(uint4*)(lds + t * 80 + i * 16) =
        make_uint4(dw[4 * i], dw[4 * i + 1], dw[4 * i + 2], dw[4 * i + 3]);
  __syncthreads();
  char* outp = Wq_t + ((size_t)bn * 64 + kt) * 16384;
#pragma unroll
  for (int i = 0; i < 4; ++i) {
    const int idx16 = t * 4 + i;
    const int wrb = idx16 >> 9, fm = (idx16 >> 6) & 7, lane = idx16 & 63;
    const int rt = wrb * 128 + fm * 16 + (lane & 15);
    *(uint4*)(outp + idx16 * 16) = *(const uint4*)(lds + rt * 80 + (lane >> 4) * 16);
  }
}

// ---------------- permute xq_tok -> fragment-tiled ----------------
__global__ void perma_kernel(const char* __restrict__ xq_tok, char* __restrict__ xq_t) {
  __shared__ __align__(16) char lds[256 * 80];
  const int bm = blockIdx.x >> 6, kt = blockIdx.x & 63;
  const int t = threadIdx.x;
#pragma unroll
  for (int p = 0; p < 4; ++p) {
    const int tok = p * 64 + (t >> 2);
    const int ch = t & 3;
    *(uint4*)(lds + tok * 80 + ch * 16) =
        *(const uint4*)(xq_tok + ((size_t)bm * 256 + tok) * K_IN + kt * 64 + ch * 16);
  }
  __syncthreads();
  char* outp = xq_t + ((size_t)bm * 64 + kt) * 16384;
#pragma unroll
  for (int i = 0; i < 4; ++i) {
    const int idx16 = t * 4 + i;
    const int wrb = idx16 >> 9, fm = (idx16 >> 6) & 7, lane = idx16 & 63;
    const int rt = wrb * 128 + fm * 16 + (lane & 15);
    *(uint4*)(outp + idx16 * 16) = *(const uint4*)(lds + rt * 80 + (lane >> 4) * 16);
  }
}

// ================= LDS-free 256x256 i8 GEMM =================
__device__ __forceinline__ i32x4 m64i8(i32x4 a, i32x4 b, i32x4 c) {
  return __builtin_amdgcn_mfma_i32_16x16x64_i8(a, b, c, 0, 0, 0);
}

#define CLUSTER(A0, A1, B0, B1, B2, B3, M0, M1)       \
  __builtin_amdgcn_s_setprio(1);                      \
  acc[M0][0] = m64i8(A0, B0, acc[M0][0]);             \
  acc[M0][1] = m64i8(A0, B1, acc[M0][1]);             \
  acc[M0][2] = m64i8(A0, B2, acc[M0][2]);             \
  acc[M0][3] = m64i8(A0, B3, acc[M0][3]);             \
  acc[M1][0] = m64i8(A1, B0, acc[M1][0]);             \
  acc[M1][1] = m64i8(A1, B1, acc[M1][1]);             \
  acc[M1][2] = m64i8(A1, B2, acc[M1][2]);             \
  acc[M1][3] = m64i8(A1, B3, acc[M1][3]);             \
  __builtin_amdgcn_s_setprio(0);

#define WAITV                                          \
  asm volatile("s_waitcnt vmcnt(10)" ::: "memory");    \
  __builtin_amdgcn_sched_barrier(0);

// One K-tile. PC* = current B frags (read all 4 clusters); PN* = next-tile B
// (loaded at tile start). A frags reload in place right after their cluster.
// Steady-state queue: entry [B(kt)x4, a0..a7(kt)] = 12; every wait = vmcnt(10).
#define TILE(PC0, PC1, PC2, PC3, PN0, PN1, PN2, PN3)   \
  {                                                    \
    const char* aN = aP + 16384;                       \
    const char* bN = bP + 16384;                       \
    PN0 = *(const i32x4*)(bN + 0);                     \
    PN1 = *(const i32x4*)(bN + 1024);                  \
    PN2 = *(const i32x4*)(bN + 2048);                  \
    PN3 = *(const i32x4*)(bN + 3072);                  \
    WAITV;                                             \
    CLUSTER(a0v, a1v, PC0, PC1, PC2, PC3, 0, 1);       \
    a0v = *(const i32x4*)(aN + 0);                     \
    a1v = *(const i32x4*)(aN + 1024);                  \
    WAITV;                                             \
    CLUSTER(a2v, a3v, PC0, PC1, PC2, PC3, 2, 3);       \
    a2v = *(const i32x4*)(aN + 2048);                  \
    a3v = *(const i32x4*)(aN + 3072);                  \
    WAITV;                                             \
    CLUSTER(a4v, a5v, PC0, PC1, PC2, PC3, 4, 5);       \
    a4v = *(const i32x4*)(aN + 4096);                  \
    a5v = *(const i32x4*)(aN + 5120);                  \
    WAITV;                                             \
    CLUSTER(a6v, a7v, PC0, PC1, PC2, PC3, 6, 7);       \
    a6v = *(const i32x4*)(aN + 6144);                  \
    a7v = *(const i32x4*)(aN + 7168);                  \
    aP = aN; bP = bN;                                  \
  }

__global__ __launch_bounds__(512, 2)
void gemm_i8(const char* __restrict__ xq_t, const char* __restrict__ Wq_t,
             const float* __restrict__ sx, const float* __restrict__ scale,
             const float* __restrict__ bias, float* __restrict__ out) {
  const int t = threadIdx.x;
  const int w = t >> 6, l = t & 63;
  const int wr = w >> 2, wc = w & 3;            // 2M x 4N waves, 128x64 each
  const int bm = blockIdx.x >> 4, bn = blockIdx.x & 15;

  const char* aP = xq_t + ((size_t)bm * 64) * 16384 + wr * 8192 + l * 16;
  const char* bP = Wq_t + ((size_t)bn * 64) * 16384 + (wc >> 1) * 8192 +
                   (wc & 1) * 4096 + l * 16;

  i32x4 acc[8][4];
#pragma unroll
  for (int m = 0; m < 8; ++m)
#pragma unroll
    for (int n = 0; n < 4; ++n) acc[m][n] = (i32x4){0, 0, 0, 0};

  i32x4 a0v, a1v, a2v, a3v, a4v, a5v, a6v, a7v;
  i32x4 p0, p1, p2, p3, q0, q1, q2, q3;

  // prologue: B(0) then A(0) -> 12 outstanding (matches steady entry state)
  p0 = *(const i32x4*)(bP + 0);
  p1 = *(const i32x4*)(bP + 1024);
  p2 = *(const i32x4*)(bP + 2048);
  p3 = *(const i32x4*)(bP + 3072);
  a0v = *(const i32x4*)(aP + 0);
  a1v = *(const i32x4*)(aP + 1024);
  a2v = *(const i32x4*)(aP + 2048);
  a3v = *(const i32x4*)(aP + 3072);
  a4v = *(const i32x4*)(aP + 4096);
  a5v = *(const i32x4*)(aP + 5120);
  a6v = *(const i32x4*)(aP + 6144);
  a7v = *(const i32x4*)(aP + 7168);

  for (int kt = 0; kt < NT; kt += 2) {
    TILE(p0, p1, p2, p3, q0, q1, q2, q3);
    TILE(q0, q1, q2, q3, p0, p1, p2, p3);
  }
  // (final iteration prefetches one tile past the end -> ws has 32KB pads)

  // ---- epilogue: C/D col=lane&15, row=(lane>>4)*4+i ; out = acc*sx[r]*sc + bias
  const int orow0 = bm * 256 + wr * 128 + ((l >> 4) << 2);
  const int ocol0 = bn * 256 + wc * 64 + (l & 15);
#pragma unroll
  for (int n = 0; n < 4; ++n) {
    const int col = ocol0 + n * 16;
    const float sc = scale[col];
    const float bi = bias[col];
#pragma unroll
    for (int m = 0; m < 8; ++m) {
      const int r = orow0 + m * 16;
      const float4 sxv = *(const float4*)(sx + r);
      out[(size_t)(r + 0) * N_O + col] = (float)acc[m][n][0] * (sxv.x * sc) + bi;
      out[(size_t)(r + 1) * N_O + col] = (float)acc[m][n][1] * (sxv.y * sc) + bi;
      out[(size_t)(r + 2) * N_O + col] = (float)acc[m][n][2] * (sxv.z * sc) + bi;
      out[(size_t)(r + 3) * N_O + col] = (float)acc[m][n][3] * (sxv.w * sc) + bi;
    }
  }
}

extern "C" void kernel_launch(void* const* d_in, const int* in_sizes, int n_in,
                              void* d_out, int out_size, void* d_ws, size_t ws_size,
                              hipStream_t stream) {
  const float* x    = (const float*)d_in[0];
  const int*   q8   = (const int*)d_in[1];
  const float* s8   = (const float*)d_in[2];
  const int*   q4   = (const int*)d_in[3];
  const float* s4   = (const float*)d_in[4];
  const int*   inv  = (const int*)d_in[5];
  const float* bias = (const float*)d_in[6];
  float* out = (float*)d_out;

  // ws: Wq_t 16M | pad 32K | xq_t 64M | pad 32K | sx 64K | scale 16K | xq_tok 64M
  char* ws = (char*)d_ws;
  char*  Wq_t   = ws;
  char*  xq_t   = ws + (16u << 20) + 32768;
  float* sx     = (float*)(xq_t + (64u << 20) + 32768);
  float* scale  = (float*)((char*)sx + 65536);
  char*  xq_tok = (char*)scale + 16384;

  prep1_kernel<<<M_TOK, 256, 0, stream>>>(x, sx, xq_tok);
  packw_kernel<<<16 * 64, 256, 0, stream>>>(q8, s8, q4, s4, inv, Wq_t, scale);
  perma_kernel<<<64 * 64, 256, 0, stream>>>(xq_tok, xq_t);
  gemm_i8<<<(M_TOK / 256) * (N_O / 256), 512, 0, stream>>>(xq_t, Wq_t, sx, scale,
                                                           bias, out);
}

// Round 7
// 374.597 us; speedup vs baseline: 1.2004x; 1.2004x over previous
//
#include <hip/hip_runtime.h>

// out[b,s,j] = sum_k x[b,s,k] * w_concat[inv_perm[j], k] + bias[j]
// INT8 path: weights exact in i8; x per-token quantized (sx = absmax/127).
// Round 6: i8 twin of the round-2 verified 4-phase 256x256 schedule.
// BK=128 i8 (128B rows == r2's BK=64 bf16 byte geometry), 8 waves, 2 barriers
// + counted vmcnt(6)/phase-4 per K-tile, st-swizzled LDS via pre-swizzled
// global_load_lds source, setprio around MFMA clusters.

#define M_TOK 16384
#define N_O   4096
#define K_IN  4096
#define N8F   2048
#define NT    (K_IN / 128)   // 32 K-tiles of BK=128 i8 (128 B/row)

typedef __attribute__((ext_vector_type(4))) int i32x4;

__device__ __forceinline__ void gl_lds16(const void* g, void* l) {
  __builtin_amdgcn_global_load_lds(
      (const __attribute__((address_space(1))) unsigned int*)g,
      (__attribute__((address_space(3))) unsigned int*)l, 16, 0, 0);
}

__device__ __forceinline__ int clampq(float f) {
  int q = (int)rintf(f);
  return q > 127 ? 127 : (q < -127 ? -127 : q);
}

// ---- fused prep: blocks [0,N_O) pack weights to i8; blocks [N_O, N_O+M_TOK)
// ---- quantize one token each (absmax -> sx, xq). Row-major i8, 4096 B rows.
__global__ void prep_kernel(const float* __restrict__ x,
                            const int4* __restrict__ q8, const float* __restrict__ s8,
                            const int4* __restrict__ q4, const float* __restrict__ s4,
                            const int* __restrict__ inv,
                            char* __restrict__ Wq, float* __restrict__ scale,
                            float* __restrict__ sx, char* __restrict__ xq) {
  __shared__ float red[4];
  const int t = threadIdx.x;
  if (blockIdx.x < N_O) {
    const int j = blockIdx.x;
    const int c = inv[j];
    const int4* src; float s;
    if (c < N8F) { src = q8 + (size_t)c * (K_IN / 4);         s = s8[c]; }
    else         { src = q4 + (size_t)(c - N8F) * (K_IN / 4); s = s4[c - N8F]; }
    if (t == 0) scale[j] = s;
    unsigned dw[4];
#pragma unroll
    for (int i = 0; i < 4; ++i) {
      int4 v = src[t * 4 + i];
      dw[i] = (v.x & 255) | ((v.y & 255) << 8) | ((v.z & 255) << 16)
            | ((unsigned)(v.w & 255) << 24);
    }
    *(uint4*)(Wq + (size_t)j * K_IN + t * 16) = make_uint4(dw[0], dw[1], dw[2], dw[3]);
  } else {
    const int T = blockIdx.x - N_O;
    const float4* xr = (const float4*)(x + (size_t)T * K_IN);
    float4 v[4];
    float m = 0.f;
#pragma unroll
    for (int i = 0; i < 4; ++i) {
      v[i] = xr[t * 4 + i];
      m = fmaxf(m, fmaxf(fmaxf(fabsf(v[i].x), fabsf(v[i].y)),
                         fmaxf(fabsf(v[i].z), fabsf(v[i].w))));
    }
#pragma unroll
    for (int o = 32; o; o >>= 1) m = fmaxf(m, __shfl_xor(m, o));
    if ((t & 63) == 0) red[t >> 6] = m;
    __syncthreads();
    m = fmaxf(fmaxf(red[0], red[1]), fmaxf(red[2], red[3]));
    const float rq = m > 0.f ? 127.f / m : 0.f;
    if (t == 0) sx[T] = m * (1.f / 127.f);
    unsigned dw[4];
#pragma unroll
    for (int i = 0; i < 4; ++i) {
      int a0 = clampq(v[i].x * rq), a1 = clampq(v[i].y * rq);
      int a2 = clampq(v[i].z * rq), a3 = clampq(v[i].w * rq);
      dw[i] = (a0 & 255) | ((a1 & 255) << 8) | ((a2 & 255) << 16)
            | ((unsigned)(a3 & 255) << 24);
    }
    *(uint4*)(xq + (size_t)T * K_IN + t * 16) = make_uint4(dw[0], dw[1], dw[2], dw[3]);
  }
}

// ================= 256x256 i8 GEMM, BK=128, r2's 4-phase schedule =================
// LDS map (bytes): buf*65536 + { A: half*16384 | B: 32768 + half*16384 }
// half = 128 rows x 128 B; swizzle: phys_colbyte = logical ^ ((row&7)<<4)
__global__ __launch_bounds__(512, 2)
void gemm_i8(const char* __restrict__ xq, const char* __restrict__ Wq,
             const float* __restrict__ sx, const float* __restrict__ scale,
             const float* __restrict__ bias, float* __restrict__ out) {
  __shared__ __align__(16) char sm[131072];
  const int t = threadIdx.x;
  const int w = t >> 6, l = t & 63;
  const int wr = w >> 2, wc = w & 3;          // 2M x 4N waves, 128x64 each
  const int bm = blockIdx.x >> 4, bn = blockIdx.x & 15;
  const int row0 = bm * 256, col0 = bn * 256;

  // --- staging: per-lane pre-swizzled global source (rule #21) ---
  const int srow = l >> 3;                              // row within 8-row group
  const int schunk = ((l & 7) ^ srow) * 16;             // inverse-swizzled 16B chunk
  const char* aG = xq + (size_t)(row0 + w * 16 + srow) * K_IN + schunk;
  const char* bG = Wq + (size_t)(col0 + w * 16 + srow) * K_IN + schunk;
  char* aL0 = sm + w * 2048;                            // + buf*65536 + h*16384
  char* bL0 = sm + 32768 + w * 2048;

  auto stageA = [&](int buf, int kt, int h) {
    const char* g = aG + (size_t)h * (128 * K_IN) + (size_t)kt * 128;
    char* p = aL0 + buf * 65536 + h * 16384;
    gl_lds16(g, p);
    gl_lds16(g + 8 * K_IN, p + 1024);
  };
  auto stageB = [&](int buf, int kt, int h) {
    const char* g = bG + (size_t)h * (128 * K_IN) + (size_t)kt * 128;
    char* p = bL0 + buf * 65536 + h * 16384;
    gl_lds16(g, p);
    gl_lds16(g + 8 * K_IN, p + 1024);
  };

  // --- fragment-read per-lane offsets (swizzled) ---
  const int lrow128 = (l & 15) * 128;
  const int cb0 = (((l >> 4) << 4) ^ ((l & 7) << 4));   // kk=0 colbyte; kk=1: ^64
  const int aWoff = wr * 16384 + lrow128;
  const int bWoff = 32768 + (wc >> 1) * 16384 + (wc & 1) * 8192 + lrow128;

  i32x4 acc[8][4];
#pragma unroll
  for (int m = 0; m < 8; ++m)
#pragma unroll
    for (int n = 0; n < 4; ++n) acc[m][n] = (i32x4){0, 0, 0, 0};

  // --- prologue: tile0 fully + tile1 {B0,B1,A0}; wait tile0 (vmcnt 14->6) ---
  stageB(0, 0, 0); stageB(0, 0, 1); stageA(0, 0, 0); stageA(0, 0, 1);
  stageB(1, 1, 0); stageB(1, 1, 1); stageA(1, 1, 0);
  asm volatile("s_waitcnt vmcnt(6)" ::: "memory");
  __builtin_amdgcn_s_barrier();

  i32x4 bfr[4][2], afr[2][2], afr2[2][2];

  for (int kt = 0; kt < NT; ++kt) {
    const int cur = kt & 1;
    const char* smA = sm + cur * 65536 + aWoff;
    const char* smB = sm + cur * 65536 + bWoff;

    // ---- phase 1: ds_read all B (8) + A mg0 (4); stage A1(kt+1) -> buf^1
#pragma unroll
    for (int n = 0; n < 4; ++n) {
      bfr[n][0] = *(const i32x4*)(smB + n * 2048 + cb0);
      bfr[n][1] = *(const i32x4*)(smB + n * 2048 + (cb0 ^ 64));
    }
#pragma unroll
    for (int m = 0; m < 2; ++m) {
      afr[m][0] = *(const i32x4*)(smA + m * 2048 + cb0);
      afr[m][1] = *(const i32x4*)(smA + m * 2048 + (cb0 ^ 64));
    }
    if (kt + 1 < NT) stageA(cur ^ 1, kt + 1, 1);
    __builtin_amdgcn_s_barrier();
    asm volatile("s_waitcnt lgkmcnt(0)" ::: "memory");
    __builtin_amdgcn_s_setprio(1);
#pragma unroll
    for (int m = 0; m < 2; ++m)
#pragma unroll
      for (int n = 0; n < 4; ++n)
#pragma unroll
        for (int kk = 0; kk < 2; ++kk)
          acc[m][n] = __builtin_amdgcn_mfma_i32_16x16x64_i8(afr[m][kk], bfr[n][kk],
                                                            acc[m][n], 0, 0, 0);
    __builtin_amdgcn_s_setprio(0);
    __builtin_amdgcn_s_barrier();

    // ---- phase 2: ds_read A mg1 (4); stage B0(kt+2) -> buf cur (region free since p1)
#pragma unroll
    for (int m = 0; m < 2; ++m) {
      afr[m][0] = *(const i32x4*)(smA + (2 + m) * 2048 + cb0);
      afr[m][1] = *(const i32x4*)(smA + (2 + m) * 2048 + (cb0 ^ 64));
    }
    if (kt + 2 < NT) stageB(cur, kt + 2, 0);
    __builtin_amdgcn_s_barrier();
    asm volatile("s_waitcnt lgkmcnt(0)" ::: "memory");
    __builtin_amdgcn_s_setprio(1);
#pragma unroll
    for (int m = 0; m < 2; ++m)
#pragma unroll
      for (int n = 0; n < 4; ++n)
#pragma unroll
        for (int kk = 0; kk < 2; ++kk)
          acc[2 + m][n] = __builtin_amdgcn_mfma_i32_16x16x64_i8(afr[m][kk], bfr[n][kk],
                                                                acc[2 + m][n], 0, 0, 0);
    __builtin_amdgcn_s_setprio(0);
    __builtin_amdgcn_s_barrier();

    // ---- phase 3: ds_read A mg2 (4) + A mg3 prefetch (4); stage B1(kt+2)
#pragma unroll
    for (int m = 0; m < 2; ++m) {
      afr[m][0]  = *(const i32x4*)(smA + (4 + m) * 2048 + cb0);
      afr[m][1]  = *(const i32x4*)(smA + (4 + m) * 2048 + (cb0 ^ 64));
      afr2[m][0] = *(const i32x4*)(smA + (6 + m) * 2048 + cb0);
      afr2[m][1] = *(const i32x4*)(smA + (6 + m) * 2048 + (cb0 ^ 64));
    }
    if (kt + 2 < NT) stageB(cur, kt + 2, 1);
    __builtin_amdgcn_s_barrier();
    asm volatile("s_waitcnt lgkmcnt(0)" ::: "memory");   // full drain: A regions reused in p4
    __builtin_amdgcn_s_setprio(1);
#pragma unroll
    for (int m = 0; m < 2; ++m)
#pragma unroll
      for (int n = 0; n < 4; ++n)
#pragma unroll
        for (int kk = 0; kk < 2; ++kk)
          acc[4 + m][n] = __builtin_amdgcn_mfma_i32_16x16x64_i8(afr[m][kk], bfr[n][kk],
                                                                acc[4 + m][n], 0, 0, 0);
    __builtin_amdgcn_s_setprio(0);
    __builtin_amdgcn_s_barrier();

    // ---- phase 4: stage A0(kt+2); counted vmcnt (drains exactly tile kt+1)
    if (kt + 2 < NT) {
      stageA(cur, kt + 2, 0);
      asm volatile("s_waitcnt vmcnt(6)" ::: "memory");
    } else {
      asm volatile("s_waitcnt vmcnt(0)" ::: "memory");
    }
    __builtin_amdgcn_s_barrier();
    __builtin_amdgcn_s_setprio(1);
#pragma unroll
    for (int m = 0; m < 2; ++m)
#pragma unroll
      for (int n = 0; n < 4; ++n)
#pragma unroll
        for (int kk = 0; kk < 2; ++kk)
          acc[6 + m][n] = __builtin_amdgcn_mfma_i32_16x16x64_i8(afr2[m][kk], bfr[n][kk],
                                                                acc[6 + m][n], 0, 0, 0);
    __builtin_amdgcn_s_setprio(0);
    __builtin_amdgcn_s_barrier();
  }

  // ---- epilogue: C/D col=lane&15, row=(lane>>4)*4+i ; out = acc*sx[r]*sc + bias
  const int orow0 = row0 + wr * 128 + ((l >> 4) << 2);
  const int ocol0 = col0 + wc * 64 + (l & 15);
#pragma unroll
  for (int n = 0; n < 4; ++n) {
    const int col = ocol0 + n * 16;
    const float sc = scale[col];
    const float bi = bias[col];
#pragma unroll
    for (int m = 0; m < 8; ++m) {
      const int r = orow0 + m * 16;
      const float4 sxv = *(const float4*)(sx + r);
      out[(size_t)(r + 0) * N_O + col] = (float)acc[m][n][0] * (sxv.x * sc) + bi;
      out[(size_t)(r + 1) * N_O + col] = (float)acc[m][n][1] * (sxv.y * sc) + bi;
      out[(size_t)(r + 2) * N_O + col] = (float)acc[m][n][2] * (sxv.z * sc) + bi;
      out[(size_t)(r + 3) * N_O + col] = (float)acc[m][n][3] * (sxv.w * sc) + bi;
    }
  }
}

extern "C" void kernel_launch(void* const* d_in, const int* in_sizes, int n_in,
                              void* d_out, int out_size, void* d_ws, size_t ws_size,
                              hipStream_t stream) {
  const float* x    = (const float*)d_in[0];
  const int*   q8   = (const int*)d_in[1];
  const float* s8   = (const float*)d_in[2];
  const int*   q4   = (const int*)d_in[3];
  const float* s4   = (const float*)d_in[4];
  const int*   inv  = (const int*)d_in[5];
  const float* bias = (const float*)d_in[6];
  float* out = (float*)d_out;

  // ws layout: Wq (16 MiB) | scale (16 KiB) | sx (64 KiB) | xq (64 MiB)
  char* ws = (char*)d_ws;
  char*  Wq    = ws;
  float* scale = (float*)(ws + (size_t)N_O * K_IN);
  float* sx    = (float*)(ws + (size_t)N_O * K_IN + 65536);
  char*  xq    = ws + (size_t)N_O * K_IN + 65536 + 65536;

  prep_kernel<<<N_O + M_TOK, 256, 0, stream>>>(x, (const int4*)q8, s8,
                                               (const int4*)q4, s4, inv,
                                               Wq, scale, sx, xq);
  gemm_i8<<<(M_TOK / 256) * (N_O / 256), 512, 0, stream>>>(xq, Wq, sx, scale,
                                                           bias, out);
}